// Round 14
// baseline (182.573 us; speedup 1.0000x reference)
//
#include <hip/hip_runtime.h>
#include <math.h>
#include <float.h>

typedef unsigned long long u64;
typedef unsigned u32;

#define NT 1024        // fallback block size
#define NW 16
#define NT1 256        // streaming block size
#define NT4 1024       // k4 block size (16 waves -> 4x gather MLP)
#define NW4 16
#define EPT4 2         // elements per thread in k4 (CAP/NT4)
#define J4 4           // bins per thread in k4 (NBM/NT4)
#define SL 8           // slices per row (k1, k3)
#define NB 8192        // 13-bit value buckets (count hist)
#define BSH 19         // key >> BSH = count bucket
#define NBM 4096       // k4 histogram bins
#define CAP 2048       // candidate capacity per row
#define SUB2 64        // mini-list capacity
#define TOPN 5
#define SCALE_D 17592186044416.0  // 2^44 fixed-point scale
#define NEG_BIG -3.0e38f          // finite stand-in for -inf on output

// k4 transposed bin address: thread t owns bins t*4+j at (j<<10)|t (lane-consecutive gathers)
#define ADDRT(g) ((((g) & 3u) << 10) | ((g) >> 2))
// padded-transposed address (k3 scan): bin g -> (g&31)*257 + (g>>5)
#define ADDRP(g) (((g) & 31u) * 257u + ((g) >> 5))

struct RowCtl { u32 kb; u32 cnt0; u32 maxKey; u32 rin; u32 bail; u32 pad[27]; };  // 128 B

__device__ __forceinline__ u32 key_of(float f){
  u32 u = __float_as_uint(f);
  return (u & 0x80000000u) ? ~u : (u | 0x80000000u);
}
__device__ __forceinline__ float key_to_float(u32 k){
  u32 u = (k & 0x80000000u) ? (k & 0x7FFFFFFFu) : ~k;
  return __uint_as_float(u);
}
__device__ __forceinline__ u64 quantMass(float l, float m){
  float ef = expf(l - m);                 // <= 1
  return (u64)((double)ef * SCALE_D + 0.5);
}

struct Top5 { float v[TOPN]; int ix[TOPN]; };
__device__ __forceinline__ void t5_init(Top5& t){
  for (int j=0;j<TOPN;j++){ t.v[j] = -INFINITY; t.ix[j] = 0x7FFFFFFF; }
}
__device__ __forceinline__ void t5_insert(Top5& t, float nv, int ni){
  for (int j=0;j<TOPN;j++){
    if (nv > t.v[j] || (nv == t.v[j] && ni < t.ix[j])){
      for (int s=TOPN-1;s>j;s--){ t.v[s]=t.v[s-1]; t.ix[s]=t.ix[s-1]; }
      t.v[j]=nv; t.ix[j]=ni;
      return;
    }
  }
}

// exclusive prefix sum over arr[0..n), arr[n]=total. 1024 threads (fallback).
__device__ void scan_excl(u64* arr, int n, u64* wsum){
  const int tid = threadIdx.x, lane = tid & 63, w = tid >> 6;
  __syncthreads();
  const int chunk = (n + NT - 1) / NT;
  const int base = tid * chunk;
  u64 local = 0;
  for (int j=0;j<chunk;j++){ int i=base+j; if (i<n) local += arr[i]; }
  u64 inc = local;
  for (int off=1; off<64; off<<=1){
    u64 up = __shfl_up(inc, off, 64);
    if (lane >= off) inc += up;
  }
  if (lane == 63) wsum[w] = inc;
  __syncthreads();
  if (tid == 0){
    u64 acc = 0;
    for (int i=0;i<NW;i++){ u64 v = wsum[i]; wsum[i] = acc; acc += v; }
    arr[n] = acc;
  }
  __syncthreads();
  u64 run = wsum[w] + (inc - local);
  for (int j=0;j<chunk;j++){ int i=base+j; if (i<n){ u64 v=arr[i]; arr[i]=run; run += v; } }
  __syncthreads();
}

// ======================= pipeline kernels =======================

__global__ void k0_zero(u32* __restrict__ hist, u32* __restrict__ ctlw, int Bn){
  size_t n = (size_t)Bn * NB;
  size_t stride = (size_t)gridDim.x * blockDim.x;
  for (size_t i = (size_t)blockIdx.x*blockDim.x + threadIdx.x; i < n; i += stride) hist[i] = 0;
  size_t nc = (size_t)Bn * (sizeof(RowCtl)/4);
  for (size_t i = (size_t)blockIdx.x*blockDim.x + threadIdx.x; i < nc; i += stride) ctlw[i] = 0;
}

__global__ __launch_bounds__(NT1) void k1_hist(const float* __restrict__ L,
        const float* __restrict__ temp, u32* __restrict__ hist, RowCtl* __restrict__ ctl,
        int Bn, int Vn){
  __shared__ u32 lh[NB];
  const int b = blockIdx.y, s = blockIdx.x, tid = threadIdx.x;
  for (int j=tid;j<NB;j+=NT1) lh[j]=0;
  const float tr = temp[b]; const float tEff = (tr < 1e-5f) ? 1.0f : tr;
  const float* Lr = L + (size_t)b*Vn;
  const int chunk = (Vn + SL-1)/SL;
  const int i0 = s*chunk, i1 = min(i0+chunk, Vn);
  __syncthreads();
  const int nv = (i1 - i0) / 4;
  const float4* L4 = (const float4*)(Lr + i0);
  u32 mk = 0;
  for (int v=tid; v<nv; v+=NT1){
    float4 x = L4[v];
    #pragma unroll
    for (int e=0;e<4;e++){
      float l = (&x.x)[e] / tEff;
      u32 k = key_of(l);
      atomicAdd(&lh[k>>BSH], 1u);
      mk = max(mk, k);
    }
  }
  for (int i=i0+nv*4+tid; i<i1; i+=NT1){
    float l = Lr[i]/tEff;
    u32 k = key_of(l);
    atomicAdd(&lh[k>>BSH], 1u);
    mk = max(mk, k);
  }
  for (int off=32; off; off>>=1){ u32 o=__shfl_xor(mk,off,64); mk=max(mk,o); }
  if ((tid&63)==0) atomicMax(&ctl[b].maxKey, mk);
  __syncthreads();
  u32* Hr = hist + (size_t)b*NB;
  for (int j=tid;j<NB;j+=NT1){ u32 c = lh[j]; if (c) atomicAdd(&Hr[j], c); }
}

// k3 v2: per-slice-block redundant (kb, rin) scan folded in, then ballot collect.
__global__ __launch_bounds__(NT1) void k3_collect(const float* __restrict__ L,
        const float* __restrict__ temp, const int* __restrict__ top_k,
        const u32* __restrict__ hist, u64* __restrict__ cand, RowCtl* __restrict__ ctl,
        int Bn, int Vn){
  __shared__ u32 lh2[32*257];     // 32.9 KB padded-transposed hist copy
  __shared__ u32 wsk[4];
  __shared__ int s_kb;
  __shared__ u32 s_rin;
  const int b = blockIdx.y, s = blockIdx.x, tid = threadIdx.x;
  const int lane = tid & 63, w = tid >> 6;
  const float tr = temp[b]; const float tEff = (tr<1e-5f)?1.0f:tr;
  const float* Lr = L + (size_t)b*Vn;
  u64* Cr = cand + (size_t)b*CAP;

  // ---- phase A: (kb, rin) from hist (redundant per block, deterministic) ----
  const u32* Hr = hist + (size_t)b*NB;
  for (int i=tid; i<NB; i+=NT1) lh2[ADDRP((u32)i)] = Hr[i];
  __syncthreads();
  u32 c32[32]; u32 lsum = 0;
  #pragma unroll
  for (int j=0;j<32;j++){ c32[j] = lh2[(u32)j*257u + (u32)tid]; lsum += c32[j]; }
  u32 inc = lsum;
  for (int off=1; off<64; off<<=1){ u32 up=__shfl_up(inc,off,64); if (lane>=off) inc+=up; }
  if (lane==63) wsk[w] = inc;
  __syncthreads();
  u32 wb = 0;
  for (int i=0;i<4;i++) if (i<w) wb += wsk[i];
  u32 run = wb + inc - lsum;
  int kk = top_k[b]; if (kk<1) kk=1; if (kk>Vn) kk=Vn;
  const u32 rank = (u32)(Vn - kk);
  #pragma unroll
  for (int j=0;j<32;j++){
    if (run <= rank && rank < run + c32[j]){ s_kb = tid*32+j; s_rin = rank - run; }
    run += c32[j];
  }
  __syncthreads();
  const u32 kb = (u32)s_kb;
  const u32 kbMinKey = kb << BSH;
  if (s == 0 && tid == 0){ ctl[b].kb = kb; ctl[b].rin = s_rin; }

  // ---- phase B: candidate collect (original, verified) ----
  const int chunk = (Vn + SL-1)/SL;
  const int i0 = s*chunk, i1 = min(i0+chunk, Vn);
  const int nv = (i1 - i0) / 4;
  const float4* L4 = (const float4*)(Lr + i0);
  for (int v=tid; v<nv; v+=NT1){
    float4 x = L4[v];
    #pragma unroll
    for (int e=0;e<4;e++){
      float l = (&x.x)[e] / tEff;
      u32 k = key_of(l);
      bool pred = (k >= kbMinKey);
      u64 mk = __ballot(pred);
      if (mk){
        int leader = __ffsll((long long)mk) - 1;
        u32 base = 0;
        if (lane == leader) base = atomicAdd(&ctl[b].cnt0, (u32)__popcll(mk));
        base = __shfl(base, leader, 64);
        if (pred){
          u32 p = base + (u32)__popcll(mk & ((1ull<<lane)-1ull));
          if (p < CAP) Cr[p] = ((u64)k<<32) | (u64)(u32)(i0 + v*4 + e);
        }
      }
    }
  }
  for (int i=i0+nv*4+tid; i<i1; i+=NT1){
    float l = Lr[i]/tEff;
    u32 k = key_of(l);
    if (k >= kbMinKey){
      u32 p = atomicAdd(&ctl[b].cnt0, 1u);
      if (p < CAP) Cr[p] = ((u64)k<<32) | (u64)(u32)i;
    }
  }
}

// k4 v9: identical algorithm to v8 (verified), widened to 1024 threads / 16 waves
// for 4x gather MLP and intra-phase latency hiding. 4 bins/thread.
__global__ __launch_bounds__(NT4) void k4_solve(const float* __restrict__ L,
        const float* __restrict__ temp, const int* __restrict__ top_k,
        const float* __restrict__ top_p, const float* __restrict__ qn,
        const u64* __restrict__ cand, RowCtl* __restrict__ ctl,
        float* __restrict__ out, int Bn, int Vn){
  __shared__ u32 cnt[NBM];        // 16 KB transposed
  __shared__ u64 mass[NBM];       // 32 KB transposed; later holds exclusive prefixes
  __shared__ u64 sub[SUB2];
  __shared__ u64 msub[SUB2];
  __shared__ u32 wsc[NW4];
  __shared__ u64 wsm[NW4];
  __shared__ u64 s_ibs[NW4];
  __shared__ int s_cnt, s_bail, s_ga, s_gb;
  __shared__ u32 s_thr, s_r3;
  __shared__ float s_fill[16];
  __shared__ Top5 s_wt5[NW4];
  __shared__ double s_wr[NW4];
  __shared__ int s_wri[NW4], s_wg[NW4];
  __shared__ u64 s_ms[NW4], s_pb[NW4];

  const int b = blockIdx.x, tid = threadIdx.x, lane = tid&63, w = tid>>6;
  const u32 n0raw = ctl[b].cnt0;
  if (n0raw == 0 || n0raw > CAP) return;      // k5 row-fallback
  const int n0 = (int)n0raw;
  const float tr = temp[b]; const float tEff = (tr<1e-5f)?1.0f:tr;
  const float* Lr = L + (size_t)b*Vn;
  const float* Qr = qn + (size_t)b*Vn;
  const u64* Cr = cand + (size_t)b*CAP;
  const u32 kb = ctl[b].kb;
  const u32 rin = ctl[b].rin;
  const u32 mKey = ctl[b].maxKey;
  const u32 kbMin = kb << BSH;
  const float m = key_to_float(mKey);

  // ---- init + load candidates + EARLY q prefetch (superset, latency-hidden) ----
  for (int i=tid;i<NBM;i+=NT4){ cnt[i]=0; mass[i]=0; }
  if (tid==0){ s_cnt=0; s_bail=0; s_ga=0; s_gb=0; s_r3=0; }
  if (tid<16) s_fill[tid] = (tid<Vn) ? Lr[tid] : 0.f;
  u64 pr[EPT4]; u32 kk_[EPT4]; bool vd[EPT4]; float qv[EPT4];
  #pragma unroll
  for (int e=0;e<EPT4;e++){
    int p = tid + e*NT4;
    vd[e] = (p < n0);
    pr[e] = vd[e] ? Cr[p] : ~0ull;
    kk_[e] = (u32)(pr[e]>>32);
  }
  #pragma unroll
  for (int e=0;e<EPT4;e++) qv[e] = vd[e] ? Qr[(u32)pr[e]] : 1.0f;

  // ---- bins + masses (mass bin does NOT need thrKey) ----
  const u32 span = mKey - kbMin;
  int shb = 0; if (span > 4095u){ int hb = 31 - __clz(span); shb = hb - 11; }
  u64 msA[EPT4]; u32 binA[EPT4], binM[EPT4]; bool inkb[EPT4];
  #pragma unroll
  for (int e=0;e<EPT4;e++){
    inkb[e] = vd[e] && ((kk_[e]>>BSH) == kb);
    binA[e] = (kk_[e] & 0x7FFFFu) >> 7;
    binM[e] = vd[e] ? ((kk_[e] - kbMin) >> shb) : 0u;
    msA[e]  = vd[e] ? quantMass(key_to_float(kk_[e]), m) : 0ull;
  }
  __syncthreads();                  // init visible
  #pragma unroll
  for (int e=0;e<EPT4;e++){
    if (inkb[e]) atomicAdd(&cnt[ADDRT(binA[e])], 1u);
    if (vd[e])   atomicAdd(&mass[ADDRT(binM[e])], msA[e]);
  }
  __syncthreads();

  // ---- dual gather + dual wave scan (conflict-free transposed) ----
  u32 c4[J4]; u64 m4[J4];
  u32 lsc = 0; u64 lsm = 0;
  #pragma unroll
  for (int j=0;j<J4;j++){
    c4[j] = cnt[(j<<10)|tid]; lsc += c4[j];
    m4[j] = mass[(j<<10)|tid]; lsm += m4[j];
  }
  u32 incc = lsc; u64 incm = lsm;
  for (int off=1;off<64;off<<=1){
    u32 uc=__shfl_up(incc,off,64); if (lane>=off) incc+=uc;
    u64 um=__shfl_up(incm,off,64); if (lane>=off) incm+=um;
  }
  if (lane==63){ wsc[w]=incc; wsm[w]=incm; }
  __syncthreads();
  u32 wbc=0; u64 wbm=0, Tall=0;
  for (int i=0;i<NW4;i++){ Tall += wsm[i]; if (i<w){ wbc += wsc[i]; wbm += wsm[i]; } }
  u32 runc = wbc + incc - lsc;
  const u64 runm = wbm + incm - lsm;
  // cnt walk -> (ga, r3); store mass prefixes back (conflict-free)
  u64 runm2 = runm;
  #pragma unroll
  for (int j=0;j<J4;j++){
    if (runc <= rin && rin < runc + c4[j]){ s_ga = tid*J4+j; s_r3 = rin - runc; }
    runc += c4[j];
    mass[(j<<10)|tid] = runm2;      // exclusive prefix of bin tid*4+j
    runm2 += m4[j];
  }
  __syncthreads();
  const int ga = s_ga; const u32 r3 = s_r3;
  // collect bin-ga
  #pragma unroll
  for (int e=0;e<EPT4;e++){
    if (inkb[e] && (int)binA[e] == ga){
      int p = atomicAdd(&s_cnt, 1);
      if (p < SUB2) sub[p] = pr[e]; else s_bail = 1;
    }
  }
  __syncthreads();
  if (s_bail){ if (tid==0) ctl[b].bail = 1; return; }
  const int ncolA = min(s_cnt, SUB2);
  for (int t=tid; t<ncolA; t+=NT4){
    u64 own = sub[t]; u32 rk = 0;
    for (int j=0;j<ncolA;j++) rk += (sub[j] < own);
    if (rk == r3) s_thr = (u32)(own>>32);
  }
  if (tid==0) s_cnt = 0;            // reset for gb collect (covered by barrier)
  __syncthreads();
  const u32 thrKey = s_thr;         // exact k-th largest key
  const int thrBin = (int)((thrKey - kbMin) >> shb);

  // ---- inBinSurv: surviving mass inside thrBin (one reduction, no loop) ----
  u64 ibs = 0;
  #pragma unroll
  for (int e=0;e<EPT4;e++)
    if (vd[e] && (int)binM[e] == thrBin && kk_[e] >= thrKey) ibs += msA[e];
  for (int off=1;off<64;off<<=1) ibs += __shfl_xor(ibs, off, 64);
  if (lane==0) s_ibs[w] = ibs;
  __syncthreads();
  u64 inB = 0;
  for (int i=0;i<NW4;i++) inB += s_ibs[i];
  const u64 prefA = (thrBin >= NBM-1) ? Tall : mass[ADDRT((u32)(thrBin+1))];
  const u64 T = Tall - prefA + inB;
  const float cf = 1.0f - top_p[b];           // ref: f32 (1.0 - top_p)
  u64 Q = (u64)((double)cf * (double)T);
  if (Q >= T) Q = T - 1;                      // ref: p_mask[:, -1] = False
  const bool inThr = (Q < inB);
  const u64 Qp = Q + prefA - inB;             // prefixAll-domain budget (when !inThr)
  if (!inThr){
    u64 run3 = runm;
    #pragma unroll
    for (int j=0;j<J4;j++){
      if (run3 <= Qp && Qp < run3 + m4[j]) s_gb = tid*J4+j;
      run3 += m4[j];
    }
  } else if (tid==0) s_gb = thrBin;
  __syncthreads();
  const int gb = s_gb;
  const u64 Pgb = inThr ? 0ull : mass[ADDRT((u32)gb)];
  const u64 Qd  = inThr ? Q : Qp;
  // collect bin-gb (key filter only needed when gb == thrBin)
  #pragma unroll
  for (int e=0;e<EPT4;e++){
    bool f = vd[e] && ((int)binM[e] == gb) && (!inThr || kk_[e] >= thrKey);
    if (f){
      int p = atomicAdd(&s_cnt, 1);
      if (p < SUB2){ sub[p] = pr[e]; msub[p] = msA[e]; } else s_bail = 1;
    }
  }
  __syncthreads();
  if (s_bail){ if (tid==0) ctl[b].bail = 1; return; }
  const int ncolB = min(s_cnt, SUB2);
  // mini prefix loop within bin gb
  u64 cacc[EPT4]; bool inb[EPT4];
  #pragma unroll
  for (int e=0;e<EPT4;e++){
    inb[e] = vd[e] && ((int)binM[e] == gb) && (!inThr || kk_[e] >= thrKey);
    cacc[e] = 0;
  }
  for (int j=0;j<ncolB;j++){
    u64 pj = sub[j]; u64 mj = msub[j];
    #pragma unroll
    for (int e=0;e<EPT4;e++)
      if (inb[e] && pj < pr[e]) cacc[e] += mj;
  }
  // local masked decision
  bool sv[EPT4]; u64 mm = 0; u64 pb = ~0ull;
  #pragma unroll
  for (int e=0;e<EPT4;e++){
    bool isSurvKey = vd[e] && kk_[e] >= thrKey;
    bool masked = false;
    if (isSurvKey){
      if ((int)binM[e] < gb) masked = true;
      else if (inb[e] && (Pgb + cacc[e] + msA[e]) <= Qd) masked = true;
    }
    sv[e] = isSurvKey && !masked;
    if (isSurvKey && masked) mm += msA[e];
    if (sv[e] && pr[e] < pb) pb = pr[e];
  }

  // ---- epilogue: Gumbel/greedy/top-5 (q already in registers), reductions ----
  Top5 t5; t5_init(t5);
  double br = -1.0; int bri = 0x7FFFFFFF; int gmin = 0x7FFFFFFF;
  #pragma unroll
  for (int e=0;e<EPT4;e++){
    if (sv[e]){
      float l = key_to_float(kk_[e]); int idx = (int)(u32)pr[e];
      double ratio = (double)expf(l - m) / (double)(-logf(qv[e]));
      if (ratio > br || (ratio == br && idx < bri)){ br = ratio; bri = idx; }
      if (kk_[e] == mKey && idx < gmin) gmin = idx;
      t5_insert(t5, l, idx);
    }
  }
  for (int off=1; off<64; off<<=1){
    Top5 o;
    for (int j=0;j<TOPN;j++){ o.v[j]=__shfl_xor(t5.v[j],off,64); o.ix[j]=__shfl_xor(t5.ix[j],off,64); }
    for (int j=0;j<TOPN;j++) t5_insert(t5, o.v[j], o.ix[j]);
    double orr = __shfl_xor(br, off, 64); int ori = __shfl_xor(bri, off, 64);
    if (orr > br || (orr == br && ori < bri)){ br = orr; bri = ori; }
    int og = __shfl_xor(gmin, off, 64); if (og < gmin) gmin = og;
    mm += __shfl_xor(mm, off, 64);
    u64 op = __shfl_xor(pb, off, 64); if (op < pb) pb = op;
  }
  if (lane==0){ s_wt5[w]=t5; s_wr[w]=br; s_wri[w]=bri; s_wg[w]=gmin; s_ms[w]=mm; s_pb[w]=pb; }
  __syncthreads();
  if (tid==0){
    Top5 f = s_wt5[0];
    double fr = s_wr[0]; int fri = s_wri[0]; int fg = s_wg[0];
    u64 fms = s_ms[0]; u64 fpb = s_pb[0];
    for (int wi=1; wi<NW4; wi++){
      for (int j=0;j<TOPN;j++) t5_insert(f, s_wt5[wi].v[j], s_wt5[wi].ix[j]);
      if (s_wr[wi] > fr || (s_wr[wi]==fr && s_wri[wi]<fri)){ fr=s_wr[wi]; fri=s_wri[wi]; }
      if (s_wg[wi] < fg) fg = s_wg[wi];
      fms += s_ms[wi];
      if (s_pb[wi] < fpb) fpb = s_pb[wi];
    }
    const u64 S2 = T - fms;
    // -inf fill: 5 smallest non-surviving vocab indices live in [0,16) whenever they matter
    int filled = 0;
    for (int i=0; i<16 && i<Vn && filled<TOPN; i++){
      float l = s_fill[i]/tEff;
      u64 pr2 = ((u64)key_of(l)<<32) | (u64)(u32)i;
      if (pr2 < fpb){ t5_insert(f, -INFINITY, i); filled++; }
    }
    double lS = log((double)S2 / SCALE_D);
    int sampled = (tr < 1e-5f) ? fg : fri;
    out[b] = (float)sampled;
    for (int j=0;j<TOPN;j++){
      float lv = f.v[j];
      float lp = (lv == -INFINITY) ? NEG_BIG : (float)((double)lv - (double)m - lS);
      out[Bn + b*TOPN + j] = lp;
      out[Bn + Bn*TOPN + b*TOPN + j] = (float)f.ix[j];
    }
  }
}

// ======================= per-row full fallback (round-2 algorithm, verified) =======================

__device__ void find_cross(const u64* arr, int n, u64 target, int* s_fh, u64* s_fb){
  const int tid = threadIdx.x;
  const int chunk = (n + NT - 1) / NT;
  const int base = tid * chunk;
  for (int j=0;j<chunk;j++){
    int i = base + j;
    if (i < n && arr[i] <= target && target < arr[i+1]){ *s_fh = i; *s_fb = arr[i]; }
  }
  __syncthreads();
}

__device__ void fallback_row(int b, const float* logits, const float* temperature,
                             const int* top_k, const float* top_p, const float* qnoise,
                             float* out, int Bn, int Vn){
  __shared__ u64 s_hist[4097];
  __shared__ u64 s_wsum[NW];
  __shared__ int s_fh;
  __shared__ u64 s_fb;
  __shared__ float s_fm[NW];
  __shared__ float s_m;
  __shared__ int s_lastMax;
  __shared__ int s_eqcnt;
  __shared__ int s_eqlist[1024];
  __shared__ int s_sel;
  __shared__ Top5 s_wt5[NW];
  __shared__ double s_wr[NW];
  __shared__ int s_wri[NW];
  __shared__ int s_wg[NW];
  __shared__ u64 s_ws2[NW];

  const int tid = threadIdx.x, lane = tid & 63, w = tid >> 6;
  const float* L  = logits + (size_t)b * Vn;
  const float* Qr = qnoise + (size_t)b * Vn;
  const float tRaw = temperature[b];
  const float tEff = (tRaw < 1e-5f) ? 1.0f : tRaw;

  for (int i=tid;i<4097;i+=NT) s_hist[i] = 0;
  if (tid==0){ s_lastMax = -1; s_eqcnt = 0; }
  __syncthreads();
  float lm = -INFINITY;
  for (int i=tid;i<Vn;i+=NT){
    float l = L[i] / tEff;
    u32 k = key_of(l);
    atomicAdd(&s_hist[k>>20], 1ull);
    lm = fmaxf(lm, l);
  }
  for (int off=32; off; off>>=1) lm = fmaxf(lm, __shfl_xor(lm, off, 64));
  if (lane==0) s_fm[w] = lm;
  scan_excl(s_hist, 4096, s_wsum);
  if (tid==0){ float mm=-INFINITY; for (int i=0;i<NW;i++) mm=fmaxf(mm,s_fm[i]); s_m=mm; }
  __syncthreads();
  const float m = s_m;

  int kk = top_k[b]; if (kk < 1) kk = 1; if (kk > Vn) kk = Vn;
  u64 r = (u64)(Vn - kk);
  find_cross(s_hist, 4096, r, &s_fh, &s_fb);
  const int kb0 = s_fh; r -= s_fb;
  __syncthreads();

  for (int i=tid;i<4097;i+=NT) s_hist[i]=0;
  __syncthreads();
  for (int i=tid;i<Vn;i+=NT){
    float l = L[i]/tEff; u32 k = key_of(l);
    if ((int)(k>>20) == kb0) atomicAdd(&s_hist[(k>>8)&0xFFFu], 1ull);
  }
  scan_excl(s_hist, 4096, s_wsum);
  find_cross(s_hist, 4096, r, &s_fh, &s_fb);
  const int kb1 = s_fh; r -= s_fb;
  __syncthreads();

  const u32 ktop24 = ((u32)kb0<<12) | (u32)kb1;
  for (int i=tid;i<4097;i+=NT) s_hist[i]=0;
  __syncthreads();
  for (int i=tid;i<Vn;i+=NT){
    float l = L[i]/tEff; u32 k = key_of(l);
    if ((k>>8) == ktop24) atomicAdd(&s_hist[k & 0xFFu], 1ull);
  }
  scan_excl(s_hist, 256, s_wsum);
  find_cross(s_hist, 256, r, &s_fh, &s_fb);
  const u32 thrKey = (ktop24<<8) | (u32)s_fh;
  const float thr = key_to_float(thrKey);
  __syncthreads();

  for (int i=tid;i<4097;i+=NT) s_hist[i]=0;
  __syncthreads();
  for (int i=tid;i<Vn;i+=NT){
    float l = L[i]/tEff;
    if (l >= thr){
      u32 k = key_of(l);
      double sd = exp((double)l - (double)m);
      u64 qv = (u64)(sd * SCALE_D + 0.5);
      atomicAdd(&s_hist[k>>20], qv);
      if (l == m) atomicMax(&s_lastMax, i);
    }
  }
  scan_excl(s_hist, 4096, s_wsum);
  const u64 T = s_hist[4096];
  const float cf = 1.0f - top_p[b];
  const double qtd = (double)cf * (double)T;
  u64 Qfix = (qtd >= (double)T) ? T : (u64)qtd;
  const bool allmask = (Qfix >= T);

  u32 vKey = 0xFFFFFFFFu;
  int idxStar = 0x7FFFFFFF;

  if (!allmask){
    find_cross(s_hist, 4096, Qfix, &s_fh, &s_fb);
    const int g0 = s_fh;
    u64 Qrem = Qfix - s_fb;
    __syncthreads();

    for (int i=tid;i<4097;i+=NT) s_hist[i]=0;
    __syncthreads();
    for (int i=tid;i<Vn;i+=NT){
      float l = L[i]/tEff;
      if (l >= thr){
        u32 k = key_of(l);
        if ((int)(k>>20) == g0){
          double sd = exp((double)l - (double)m);
          atomicAdd(&s_hist[(k>>8)&0xFFFu], (u64)(sd*SCALE_D+0.5));
        }
      }
    }
    scan_excl(s_hist, 4096, s_wsum);
    find_cross(s_hist, 4096, Qrem, &s_fh, &s_fb);
    const int g1 = s_fh; Qrem -= s_fb;
    __syncthreads();

    const u32 ptop24 = ((u32)g0<<12)|(u32)g1;
    for (int i=tid;i<4097;i+=NT) s_hist[i]=0;
    __syncthreads();
    for (int i=tid;i<Vn;i+=NT){
      float l = L[i]/tEff;
      if (l >= thr){
        u32 k = key_of(l);
        if ((k>>8) == ptop24){
          double sd = exp((double)l - (double)m);
          atomicAdd(&s_hist[k & 0xFFu], (u64)(sd*SCALE_D+0.5));
        }
      }
    }
    scan_excl(s_hist, 256, s_wsum);
    find_cross(s_hist, 256, Qrem, &s_fh, &s_fb);
    const int g2 = s_fh;
    const u64 base2 = s_fb;
    const u64 nextPref = s_hist[g2+1];
    Qrem -= base2;
    vKey = (ptop24<<8) | (u32)g2;
    const float vStar = key_to_float(vKey);
    const double sv = exp((double)vStar - (double)m);
    const u64 qstar = (u64)(sv*SCALE_D+0.5);
    u64 nstar = (qstar > 0) ? (nextPref - base2) / qstar : 1ull;
    if (nstar < 1) nstar = 1;
    u64 tmask = (qstar > 0) ? (Qrem / qstar) : 0ull;
    if (tmask >= nstar) tmask = nstar - 1;
    idxStar = -1;
    __syncthreads();
    if (tmask >= 1){
      for (int i=tid;i<Vn;i+=NT){
        float l = L[i]/tEff;
        if (key_of(l) == vKey){
          int p = atomicAdd(&s_eqcnt, 1);
          if (p < 1024) s_eqlist[p] = i;
        }
      }
      __syncthreads();
      if (tid == 0){
        int n_ = s_eqcnt; if (n_ > 1024) n_ = 1024;
        for (int a=1;a<n_;a++){
          int key0 = s_eqlist[a]; int c2=a-1;
          while (c2>=0 && s_eqlist[c2]>key0){ s_eqlist[c2+1]=s_eqlist[c2]; c2--; }
          s_eqlist[c2+1]=key0;
        }
        int ti = (int)tmask - 1;
        if (ti >= n_) ti = n_-1;
        s_sel = s_eqlist[ti];
      }
      __syncthreads();
      idxStar = s_sel;
    }
  }

  const int lastMax = s_lastMax;
  Top5 t5; t5_init(t5);
  u64 s2 = 0;
  double br = -1.0; int bri = 0x7FFFFFFF;
  int gmin = 0x7FFFFFFF;
  for (int i=tid;i<Vn;i+=NT){
    float l = L[i]/tEff;
    u32 k = key_of(l);
    bool surv = (l >= thr) &&
                ((k > vKey) || (k == vKey && i > idxStar) || (i == lastMax));
    float val;
    if (surv){
      double sd = exp((double)l - (double)m);
      s2 += (u64)(sd*SCALE_D+0.5);
      float u = expf(l - m);
      float e = -logf(Qr[i]);
      double ratio = (double)u / (double)e;
      if (ratio > br || (ratio == br && i < bri)){ br = ratio; bri = i; }
      if (l == m && i < gmin) gmin = i;
      val = l;
    } else {
      val = -INFINITY;
    }
    t5_insert(t5, val, i);
  }
  for (int off=1; off<64; off<<=1){
    Top5 o;
    for (int j=0;j<TOPN;j++){ o.v[j]=__shfl_xor(t5.v[j],off,64); o.ix[j]=__shfl_xor(t5.ix[j],off,64); }
    for (int j=0;j<TOPN;j++) t5_insert(t5, o.v[j], o.ix[j]);
    double orr = __shfl_xor(br, off, 64);
    int ori = __shfl_xor(bri, off, 64);
    if (orr > br || (orr == br && ori < bri)){ br = orr; bri = ori; }
    int og = __shfl_xor(gmin, off, 64); if (og < gmin) gmin = og;
    s2 += __shfl_xor(s2, off, 64);
  }
  if (lane == 0){
    s_wt5[w] = t5; s_wr[w]=br; s_wri[w]=bri; s_wg[w]=gmin; s_ws2[w]=s2;
  }
  __syncthreads();
  if (tid == 0){
    Top5 f = s_wt5[0];
    double fr = s_wr[0]; int fri = s_wri[0]; int fg = s_wg[0];
    u64 fs2 = s_ws2[0];
    for (int wi=1; wi<NW; wi++){
      for (int j=0;j<TOPN;j++) t5_insert(f, s_wt5[wi].v[j], s_wt5[wi].ix[j]);
      if (s_wr[wi] > fr || (s_wr[wi]==fr && s_wri[wi]<fri)){ fr=s_wr[wi]; fri=s_wri[wi]; }
      if (s_wg[wi] < fg) fg = s_wg[wi];
      fs2 += s_ws2[wi];
    }
    double S2d = (double)fs2 / SCALE_D;
    double lS = log(S2d);
    int sampled = (tRaw < 1e-5f) ? fg : fri;
    out[b] = (float)sampled;
    for (int j=0;j<TOPN;j++){
      float lv = f.v[j];
      float lp = (lv == -INFINITY) ? NEG_BIG : (float)((double)lv - (double)m - lS);
      out[Bn + b*TOPN + j] = lp;
      out[Bn + Bn*TOPN + b*TOPN + j] = (float)f.ix[j];
    }
  }
}

__global__ __launch_bounds__(NT) void k5_rowfb(const float* __restrict__ logits,
        const float* __restrict__ temperature, const int* __restrict__ top_k,
        const float* __restrict__ top_p, const float* __restrict__ qnoise,
        const RowCtl* __restrict__ ctl, float* __restrict__ out, int Bn, int Vn){
  const int b = blockIdx.x;
  const u32 c = ctl[b].cnt0;
  if (c > 0 && c <= CAP && !ctl[b].bail) return;   // handled by k4
  fallback_row(b, logits, temperature, top_k, top_p, qnoise, out, Bn, Vn);
}

extern "C" __global__ void __launch_bounds__(NT)
sampler_fallback(const float* __restrict__ logits, const float* __restrict__ temperature,
                 const int* __restrict__ top_k, const float* __restrict__ top_p,
                 const float* __restrict__ qnoise, float* __restrict__ out, int Bn, int Vn){
  fallback_row(blockIdx.x, logits, temperature, top_k, top_p, qnoise, out, Bn, Vn);
}

// ======================= launch =======================

extern "C" void kernel_launch(void* const* d_in, const int* in_sizes, int n_in,
                              void* d_out, int out_size, void* d_ws, size_t ws_size,
                              hipStream_t stream)
{
  const float* logits      = (const float*)d_in[0];
  const float* temperature = (const float*)d_in[1];
  const int*   top_k       = (const int*)d_in[2];
  const float* top_p       = (const float*)d_in[3];
  const float* q           = (const float*)d_in[4];
  const int Bn = in_sizes[1];
  const int Vn = in_sizes[0] / Bn;

  const size_t offCand = (size_t)Bn * NB * 4;                 // hist u32
  const size_t offCtl  = offCand + (size_t)Bn * CAP * 8;      // cand u64
  const size_t total   = offCtl + (size_t)Bn * sizeof(RowCtl);

  if (ws_size < total){
    sampler_fallback<<<dim3(Bn), dim3(NT), 0, stream>>>(
        logits, temperature, top_k, top_p, q, (float*)d_out, Bn, Vn);
    return;
  }

  char* wsb = (char*)d_ws;
  u32*    hist = (u32*)wsb;
  u64*    cand = (u64*)(wsb + offCand);
  RowCtl* ctl  = (RowCtl*)(wsb + offCtl);

  k0_zero   <<<dim3(512),     dim3(256), 0, stream>>>(hist, (u32*)ctl, Bn);
  k1_hist   <<<dim3(SL, Bn),  dim3(NT1), 0, stream>>>(logits, temperature, hist, ctl, Bn, Vn);
  k3_collect<<<dim3(SL, Bn),  dim3(NT1), 0, stream>>>(logits, temperature, top_k, hist,
                                                      cand, ctl, Bn, Vn);
  k4_solve  <<<dim3(Bn),      dim3(NT4), 0, stream>>>(logits, temperature, top_k, top_p, q,
                                                      cand, ctl, (float*)d_out, Bn, Vn);
  k5_rowfb  <<<dim3(Bn),      dim3(NT),  0, stream>>>(logits, temperature, top_k, top_p, q,
                                                      ctl, (float*)d_out, Bn, Vn);
}

// Round 15
// 128.797 us; speedup vs baseline: 1.4175x; 1.4175x over previous
//
#include <hip/hip_runtime.h>
#include <math.h>
#include <float.h>

typedef unsigned long long u64;
typedef unsigned u32;

#define NT 1024        // fallback + k2 block size
#define NW 16
#define NT1 256        // streaming + k4 block size
#define SL 8           // slices per row (k1, k3)
#define NB 8192        // 13-bit value buckets (count hist)
#define BSH 19         // key >> BSH = count bucket
#define NBM 4096       // k4 histogram bins
#define CAP 2048       // candidate capacity per row
#define EPT4 8         // elements per thread in k4
#define SUB2 64        // mini-list capacity
#define TOPN 5
#define SCALE_D 17592186044416.0  // 2^44 fixed-point scale
#define NEG_BIG -3.0e38f          // finite stand-in for -inf on output

// transposed bin address: bin g -> ((g&15)<<8)|(g>>4); thread t's bins t*16+j sit at (j<<8)|t
#define ADDRT(g) ((((g) & 15u) << 8) | ((g) >> 4))

struct RowCtl { u32 kb; u32 cnt0; u32 maxKey; u32 rin; u32 bail; u32 pad[27]; };  // 128 B

__device__ __forceinline__ u32 key_of(float f){
  u32 u = __float_as_uint(f);
  return (u & 0x80000000u) ? ~u : (u | 0x80000000u);
}
__device__ __forceinline__ float key_to_float(u32 k){
  u32 u = (k & 0x80000000u) ? (k & 0x7FFFFFFFu) : ~k;
  return __uint_as_float(u);
}
__device__ __forceinline__ u64 quantMass(float l, float m){
  float ef = expf(l - m);                 // <= 1
  return (u64)((double)ef * SCALE_D + 0.5);
}

struct Top5 { float v[TOPN]; int ix[TOPN]; };
__device__ __forceinline__ void t5_init(Top5& t){
  for (int j=0;j<TOPN;j++){ t.v[j] = -INFINITY; t.ix[j] = 0x7FFFFFFF; }
}
__device__ __forceinline__ void t5_insert(Top5& t, float nv, int ni){
  for (int j=0;j<TOPN;j++){
    if (nv > t.v[j] || (nv == t.v[j] && ni < t.ix[j])){
      for (int s=TOPN-1;s>j;s--){ t.v[s]=t.v[s-1]; t.ix[s]=t.ix[s-1]; }
      t.v[j]=nv; t.ix[j]=ni;
      return;
    }
  }
}

// exclusive prefix sum over arr[0..n), arr[n]=total. 1024 threads (fallback).
__device__ void scan_excl(u64* arr, int n, u64* wsum){
  const int tid = threadIdx.x, lane = tid & 63, w = tid >> 6;
  __syncthreads();
  const int chunk = (n + NT - 1) / NT;
  const int base = tid * chunk;
  u64 local = 0;
  for (int j=0;j<chunk;j++){ int i=base+j; if (i<n) local += arr[i]; }
  u64 inc = local;
  for (int off=1; off<64; off<<=1){
    u64 up = __shfl_up(inc, off, 64);
    if (lane >= off) inc += up;
  }
  if (lane == 63) wsum[w] = inc;
  __syncthreads();
  if (tid == 0){
    u64 acc = 0;
    for (int i=0;i<NW;i++){ u64 v = wsum[i]; wsum[i] = acc; acc += v; }
    arr[n] = acc;
  }
  __syncthreads();
  u64 run = wsum[w] + (inc - local);
  for (int j=0;j<chunk;j++){ int i=base+j; if (i<n){ u64 v=arr[i]; arr[i]=run; run += v; } }
  __syncthreads();
}

// ======================= pipeline kernels =======================

__global__ __launch_bounds__(NT1) void k1_hist(const float* __restrict__ L,
        const float* __restrict__ temp, u32* __restrict__ hist, RowCtl* __restrict__ ctl,
        int Bn, int Vn){
  __shared__ u32 lh[NB];
  const int b = blockIdx.y, s = blockIdx.x, tid = threadIdx.x;
  for (int j=tid;j<NB;j+=NT1) lh[j]=0;
  const float tr = temp[b]; const float tEff = (tr < 1e-5f) ? 1.0f : tr;
  const float* Lr = L + (size_t)b*Vn;
  const int chunk = (Vn + SL-1)/SL;
  const int i0 = s*chunk, i1 = min(i0+chunk, Vn);
  __syncthreads();
  const int nv = (i1 - i0) / 4;
  const float4* L4 = (const float4*)(Lr + i0);
  u32 mk = 0;
  for (int v=tid; v<nv; v+=NT1){
    float4 x = L4[v];
    #pragma unroll
    for (int e=0;e<4;e++){
      float l = (&x.x)[e] / tEff;
      u32 k = key_of(l);
      atomicAdd(&lh[k>>BSH], 1u);
      mk = max(mk, k);
    }
  }
  for (int i=i0+nv*4+tid; i<i1; i+=NT1){
    float l = Lr[i]/tEff;
    u32 k = key_of(l);
    atomicAdd(&lh[k>>BSH], 1u);
    mk = max(mk, k);
  }
  for (int off=32; off; off>>=1){ u32 o=__shfl_xor(mk,off,64); mk=max(mk,o); }
  if ((tid&63)==0) atomicMax(&ctl[b].maxKey, mk);
  __syncthreads();
  u32* Hr = hist + (size_t)b*NB;
  for (int j=tid;j<NB;j+=NT1){ u32 c = lh[j]; if (c) atomicAdd(&Hr[j], c); }
}

__global__ __launch_bounds__(NT) void k2_kb(const int* __restrict__ top_k,
        const u32* __restrict__ hist, RowCtl* __restrict__ ctl, int Bn, int Vn){
  __shared__ u32 sh[NB+1];
  __shared__ u32 wsum[NW];
  __shared__ int s_g;
  __shared__ u32 s_base;
  const int b = blockIdx.x, tid = threadIdx.x, lane = tid&63, w = tid>>6;
  const u32* Hr = hist + (size_t)b*NB;
  for (int j=tid;j<NB;j+=NT) sh[j] = Hr[j];
  __syncthreads();
  const int chunk = NB/NT;  // 8
  u32 local=0;
  for (int j=0;j<chunk;j++) local += sh[tid*chunk+j];
  u32 inc = local;
  for (int off=1;off<64;off<<=1){ u32 up=__shfl_up(inc,off,64); if (lane>=off) inc+=up; }
  if (lane==63) wsum[w]=inc;
  __syncthreads();
  if (tid==0){ u32 acc=0; for(int i=0;i<NW;i++){u32 v=wsum[i]; wsum[i]=acc; acc+=v;} sh[NB]=acc; }
  __syncthreads();
  u32 run = wsum[w] + (inc - local);
  for (int j=0;j<chunk;j++){ int i2=tid*chunk+j; u32 v=sh[i2]; sh[i2]=run; run+=v; }
  __syncthreads();
  int kk = top_k[b]; if (kk<1) kk=1; if (kk>Vn) kk=Vn;
  const u32 rank = (u32)(Vn - kk);
  for (int j=tid;j<NB;j+=NT) if (sh[j] <= rank && rank < sh[j+1]){ s_g = j; s_base = sh[j]; }
  __syncthreads();
  if (tid==0){ ctl[b].kb = (u32)s_g; ctl[b].rin = rank - s_base; }
}

__global__ __launch_bounds__(NT1) void k3_collect(const float* __restrict__ L,
        const float* __restrict__ temp, u64* __restrict__ cand, RowCtl* __restrict__ ctl,
        int Bn, int Vn){
  const int b = blockIdx.y, s = blockIdx.x, tid = threadIdx.x;
  const float tr = temp[b]; const float tEff = (tr<1e-5f)?1.0f:tr;
  const u32 kbMinKey = ctl[b].kb << BSH;
  const float* Lr = L + (size_t)b*Vn;
  u64* Cr = cand + (size_t)b*CAP;
  const int chunk = (Vn + SL-1)/SL;
  const int i0 = s*chunk, i1 = min(i0+chunk, Vn);
  const int nv = (i1 - i0) / 4;
  const float4* L4 = (const float4*)(Lr + i0);
  const int lane = tid & 63;
  for (int v=tid; v<nv; v+=NT1){
    float4 x = L4[v];
    #pragma unroll
    for (int e=0;e<4;e++){
      float l = (&x.x)[e] / tEff;
      u32 k = key_of(l);
      bool pred = (k >= kbMinKey);
      u64 mk = __ballot(pred);
      if (mk){
        int leader = __ffsll((long long)mk) - 1;
        u32 base = 0;
        if (lane == leader) base = atomicAdd(&ctl[b].cnt0, (u32)__popcll(mk));
        base = __shfl(base, leader, 64);
        if (pred){
          u32 p = base + (u32)__popcll(mk & ((1ull<<lane)-1ull));
          if (p < CAP) Cr[p] = ((u64)k<<32) | (u64)(u32)(i0 + v*4 + e);
        }
      }
    }
  }
  for (int i=i0+nv*4+tid; i<i1; i+=NT1){
    float l = Lr[i]/tEff;
    u32 k = key_of(l);
    if (k >= kbMinKey){
      u32 p = atomicAdd(&ctl[b].cnt0, 1u);
      if (p < CAP) Cr[p] = ((u64)k<<32) | (u64)(u32)i;
    }
  }
}

// k4 v7 (round-11 verified, best measured): two-level histogram select with
// TRANSPOSED bins + register scans. No scan write-back, no find-cross passes.
__global__ __launch_bounds__(NT1) void k4_solve(const float* __restrict__ L,
        const float* __restrict__ temp, const int* __restrict__ top_k,
        const float* __restrict__ top_p, const float* __restrict__ qn,
        const u64* __restrict__ cand, RowCtl* __restrict__ ctl,
        float* __restrict__ out, int Bn, int Vn){
  __shared__ u32 cnt[NBM];        // 16 KB (transposed bins)
  __shared__ u64 mass[NBM];       // 32 KB (transposed bins)
  __shared__ u64 sub[SUB2];
  __shared__ u64 msub[SUB2];
  __shared__ u32 wsc[4];
  __shared__ u64 wsm[4];
  __shared__ int s_cnt, s_bail, s_ga, s_gb;
  __shared__ u32 s_thr, s_r3;
  __shared__ u64 s_Pgb;
  __shared__ float s_fill[16];
  __shared__ Top5 s_wt5[4];
  __shared__ double s_wr[4];
  __shared__ int s_wri[4], s_wg[4];
  __shared__ u64 s_ms[4], s_pb[4];

  const int b = blockIdx.x, tid = threadIdx.x, lane = tid&63, w = tid>>6;
  const u32 n0raw = ctl[b].cnt0;
  if (n0raw == 0 || n0raw > CAP) return;      // k5 row-fallback
  const int n0 = (int)n0raw;
  const float tr = temp[b]; const float tEff = (tr<1e-5f)?1.0f:tr;
  const float* Lr = L + (size_t)b*Vn;
  const float* Qr = qn + (size_t)b*Vn;
  const u64* Cr = cand + (size_t)b*CAP;
  const u32 kb = ctl[b].kb;
  const u32 rin = ctl[b].rin;
  const u32 mKey = ctl[b].maxKey;
  const float m = key_to_float(mKey);

  // ---- init + load own candidates (coalesced) ----
  for (int i=tid;i<NBM;i+=NT1){ cnt[i]=0; mass[i]=0; }
  if (tid==0){ s_cnt=0; s_bail=0; s_ga=0; s_gb=0; s_r3=0; s_Pgb=0; }
  if (tid<16) s_fill[tid] = (tid<Vn) ? Lr[tid] : 0.f;
  u64 pr[EPT4]; u32 kk_[EPT4]; bool vd[EPT4];
  #pragma unroll
  for (int e=0;e<EPT4;e++){
    int p = tid + e*NT1;
    vd[e] = (p < n0);
    pr[e] = vd[e] ? Cr[p] : ~0ull;
    kk_[e] = (u32)(pr[e]>>32);
  }
  __syncthreads();

  // ---- level A: count hist over bucket-kb low 19 bits (bins = bits 18..7) ----
  bool inkb[EPT4]; u32 binA[EPT4];
  #pragma unroll
  for (int e=0;e<EPT4;e++){
    inkb[e] = vd[e] && ((kk_[e]>>BSH) == kb);
    binA[e] = (kk_[e] & 0x7FFFFu) >> 7;
    if (inkb[e]) atomicAdd(&cnt[ADDRT(binA[e])], 1u);
  }
  __syncthreads();
  // register gather (conflict-free) + wave scan + local crossing detection
  {
    u32 c16[16]; u32 lsum = 0;
    #pragma unroll
    for (int j=0;j<16;j++){ c16[j] = cnt[(j<<8)|tid]; lsum += c16[j]; }
    u32 inc = lsum;
    for (int off=1;off<64;off<<=1){ u32 up=__shfl_up(inc,off,64); if (lane>=off) inc+=up; }
    if (lane==63) wsc[w] = inc;
    __syncthreads();
    u32 wb = 0;
    for (int i=0;i<4;i++) if (i<w) wb += wsc[i];
    u32 run = wb + inc - lsum;
    #pragma unroll
    for (int j=0;j<16;j++){
      if (run <= rin && rin < run + c16[j]){ s_ga = tid*16+j; s_r3 = rin - run; }
      run += c16[j];
    }
  }
  __syncthreads();
  const int ga = s_ga;
  const u32 r3 = s_r3;
  // collect bin-ga elements
  #pragma unroll
  for (int e=0;e<EPT4;e++){
    if (inkb[e] && (int)binA[e] == ga){
      int p = atomicAdd(&s_cnt, 1);
      if (p < SUB2) sub[p] = pr[e]; else s_bail = 1;
    }
  }
  __syncthreads();
  if (s_bail){ if (tid==0) ctl[b].bail = 1; return; }
  const int ncolA = min(s_cnt, SUB2);
  // mini rank loop (ncolA expected 1-8)
  for (int t=tid; t<ncolA; t+=NT1){
    u64 own = sub[t]; u32 rk = 0;
    for (int j=0;j<ncolA;j++) rk += (sub[j] < own);
    if (rk == r3) s_thr = (u32)(own>>32);
  }
  __syncthreads();
  const u32 thrKey = s_thr;   // exact k-th largest key

  // ---- survivor masses + level-B mass histogram ----
  u64 ms_[EPT4];
  const u32 span = mKey - thrKey;
  int shb = 0;
  if (span > 4095u){ int hb = 31 - __clz(span); shb = hb - 11; }
  u32 binB[EPT4];
  if (tid==0) s_cnt = 0;      // reset for B's collect (covered by next barrier)
  #pragma unroll
  for (int e=0;e<EPT4;e++){
    ms_[e] = (vd[e] && kk_[e] >= thrKey) ? quantMass(key_to_float(kk_[e]), m) : 0ull;
    binB[e] = ms_[e] ? ((kk_[e] - thrKey) >> shb) : 0u;
    if (ms_[e]) atomicAdd(&mass[ADDRT(binB[e])], ms_[e]);
  }
  __syncthreads();
  // register gather + wave scan; T = total; detect budget crossing locally
  u64 Qq = 0, Tt = 0;
  {
    u64 m16[16]; u64 lsm = 0;
    #pragma unroll
    for (int j=0;j<16;j++){ m16[j] = mass[(j<<8)|tid]; lsm += m16[j]; }
    u64 incm = lsm;
    for (int off=1;off<64;off<<=1){ u64 up=__shfl_up(incm,off,64); if (lane>=off) incm+=up; }
    if (lane==63) wsm[w] = incm;
    __syncthreads();
    u64 wbm = 0, T = 0;
    for (int i=0;i<4;i++){ T += wsm[i]; if (i<w) wbm += wsm[i]; }
    const float cf = 1.0f - top_p[b];         // ref: f32 (1.0 - top_p)
    u64 Q = (u64)((double)cf * (double)T);
    if (Q >= T) Q = T - 1;                    // ref: p_mask[:, -1] = False
    u64 run = wbm + incm - lsm;
    #pragma unroll
    for (int j=0;j<16;j++){
      if (run <= Q && Q < run + m16[j]){ s_gb = tid*16+j; s_Pgb = run; }
      run += m16[j];
    }
    Qq = Q; Tt = T;
  }
  __syncthreads();
  const int gb = s_gb;
  const u64 Pgb = s_Pgb;
  const u64 Q = Qq, T = Tt;
  // collect bin-gb elements (+masses)
  #pragma unroll
  for (int e=0;e<EPT4;e++){
    if (ms_[e] && (int)binB[e] == gb){
      int p = atomicAdd(&s_cnt, 1);
      if (p < SUB2){ sub[p] = pr[e]; msub[p] = ms_[e]; } else s_bail = 1;
    }
  }
  __syncthreads();
  if (s_bail){ if (tid==0) ctl[b].bail = 1; return; }
  const int ncolB = min(s_cnt, SUB2);
  // mini prefix loop: per own in-bin element, mass of in-bin elements before it
  u64 cacc[EPT4];
  bool inb[EPT4];
  #pragma unroll
  for (int e=0;e<EPT4;e++){ cacc[e]=0; inb[e] = (ms_[e] != 0) && ((int)binB[e] == gb); }
  for (int j=0;j<ncolB;j++){
    u64 pj = sub[j]; u64 mj = msub[j];
    #pragma unroll
    for (int e=0;e<EPT4;e++)
      if (inb[e] && pj < pr[e]) cacc[e] += mj;
  }
  // local masked decision
  bool sv[EPT4];
  u64 mm = 0; u64 pb = ~0ull;
  #pragma unroll
  for (int e=0;e<EPT4;e++){
    bool masked = false;
    if (ms_[e]){
      if ((int)binB[e] < gb) masked = true;
      else if ((int)binB[e] == gb && (Pgb + cacc[e] + ms_[e]) <= Q) masked = true;
    }
    sv[e] = (ms_[e] != 0) && !masked;
    if (masked) mm += ms_[e];
    if (sv[e] && pr[e] < pb) pb = pr[e];
  }

  // ---- epilogue: gather q, Gumbel/greedy/top-5, reductions ----
  float qv[EPT4];
  #pragma unroll
  for (int e=0;e<EPT4;e++) qv[e] = sv[e] ? Qr[(u32)pr[e]] : 1.0f;
  Top5 t5; t5_init(t5);
  double br = -1.0; int bri = 0x7FFFFFFF; int gmin = 0x7FFFFFFF;
  #pragma unroll
  for (int e=0;e<EPT4;e++){
    if (sv[e]){
      float l = key_to_float(kk_[e]); int idx = (int)(u32)pr[e];
      double ratio = (double)expf(l - m) / (double)(-logf(qv[e]));
      if (ratio > br || (ratio == br && idx < bri)){ br = ratio; bri = idx; }
      if (kk_[e] == mKey && idx < gmin) gmin = idx;
      t5_insert(t5, l, idx);
    }
  }
  for (int off=1; off<64; off<<=1){
    Top5 o;
    for (int j=0;j<TOPN;j++){ o.v[j]=__shfl_xor(t5.v[j],off,64); o.ix[j]=__shfl_xor(t5.ix[j],off,64); }
    for (int j=0;j<TOPN;j++) t5_insert(t5, o.v[j], o.ix[j]);
    double orr = __shfl_xor(br, off, 64); int ori = __shfl_xor(bri, off, 64);
    if (orr > br || (orr == br && ori < bri)){ br = orr; bri = ori; }
    int og = __shfl_xor(gmin, off, 64); if (og < gmin) gmin = og;
    mm += __shfl_xor(mm, off, 64);
    u64 op = __shfl_xor(pb, off, 64); if (op < pb) pb = op;
  }
  if (lane==0){ s_wt5[w]=t5; s_wr[w]=br; s_wri[w]=bri; s_wg[w]=gmin; s_ms[w]=mm; s_pb[w]=pb; }
  __syncthreads();
  if (tid==0){
    Top5 f = s_wt5[0];
    double fr = s_wr[0]; int fri = s_wri[0]; int fg = s_wg[0];
    u64 fms = s_ms[0]; u64 fpb = s_pb[0];
    for (int wi=1; wi<4; wi++){
      for (int j=0;j<TOPN;j++) t5_insert(f, s_wt5[wi].v[j], s_wt5[wi].ix[j]);
      if (s_wr[wi] > fr || (s_wr[wi]==fr && s_wri[wi]<fri)){ fr=s_wr[wi]; fri=s_wri[wi]; }
      if (s_wg[wi] < fg) fg = s_wg[wi];
      fms += s_ms[wi];
      if (s_pb[wi] < fpb) fpb = s_pb[wi];
    }
    const u64 S2 = T - fms;
    // -inf fill: 5 smallest non-surviving vocab indices live in [0,16) whenever they matter
    int filled = 0;
    for (int i=0; i<16 && i<Vn && filled<TOPN; i++){
      float l = s_fill[i]/tEff;
      u64 pr2 = ((u64)key_of(l)<<32) | (u64)(u32)i;
      if (pr2 < fpb){ t5_insert(f, -INFINITY, i); filled++; }
    }
    double lS = log((double)S2 / SCALE_D);
    int sampled = (tr < 1e-5f) ? fg : fri;
    out[b] = (float)sampled;
    for (int j=0;j<TOPN;j++){
      float lv = f.v[j];
      float lp = (lv == -INFINITY) ? NEG_BIG : (float)((double)lv - (double)m - lS);
      out[Bn + b*TOPN + j] = lp;
      out[Bn + Bn*TOPN + b*TOPN + j] = (float)f.ix[j];
    }
  }
}

// ======================= per-row full fallback (round-2 algorithm, verified) =======================

__device__ void find_cross(const u64* arr, int n, u64 target, int* s_fh, u64* s_fb){
  const int tid = threadIdx.x;
  const int chunk = (n + NT - 1) / NT;
  const int base = tid * chunk;
  for (int j=0;j<chunk;j++){
    int i = base + j;
    if (i < n && arr[i] <= target && target < arr[i+1]){ *s_fh = i; *s_fb = arr[i]; }
  }
  __syncthreads();
}

__device__ void fallback_row(int b, const float* logits, const float* temperature,
                             const int* top_k, const float* top_p, const float* qnoise,
                             float* out, int Bn, int Vn){
  __shared__ u64 s_hist[4097];
  __shared__ u64 s_wsum[NW];
  __shared__ int s_fh;
  __shared__ u64 s_fb;
  __shared__ float s_fm[NW];
  __shared__ float s_m;
  __shared__ int s_lastMax;
  __shared__ int s_eqcnt;
  __shared__ int s_eqlist[1024];
  __shared__ int s_sel;
  __shared__ Top5 s_wt5[NW];
  __shared__ double s_wr[NW];
  __shared__ int s_wri[NW];
  __shared__ int s_wg[NW];
  __shared__ u64 s_ws2[NW];

  const int tid = threadIdx.x, lane = tid & 63, w = tid >> 6;
  const float* L  = logits + (size_t)b * Vn;
  const float* Qr = qnoise + (size_t)b * Vn;
  const float tRaw = temperature[b];
  const float tEff = (tRaw < 1e-5f) ? 1.0f : tRaw;

  for (int i=tid;i<4097;i+=NT) s_hist[i] = 0;
  if (tid==0){ s_lastMax = -1; s_eqcnt = 0; }
  __syncthreads();
  float lm = -INFINITY;
  for (int i=tid;i<Vn;i+=NT){
    float l = L[i] / tEff;
    u32 k = key_of(l);
    atomicAdd(&s_hist[k>>20], 1ull);
    lm = fmaxf(lm, l);
  }
  for (int off=32; off; off>>=1) lm = fmaxf(lm, __shfl_xor(lm, off, 64));
  if (lane==0) s_fm[w] = lm;
  scan_excl(s_hist, 4096, s_wsum);
  if (tid==0){ float mm=-INFINITY; for (int i=0;i<NW;i++) mm=fmaxf(mm,s_fm[i]); s_m=mm; }
  __syncthreads();
  const float m = s_m;

  int kk = top_k[b]; if (kk < 1) kk = 1; if (kk > Vn) kk = Vn;
  u64 r = (u64)(Vn - kk);
  find_cross(s_hist, 4096, r, &s_fh, &s_fb);
  const int kb0 = s_fh; r -= s_fb;
  __syncthreads();

  for (int i=tid;i<4097;i+=NT) s_hist[i]=0;
  __syncthreads();
  for (int i=tid;i<Vn;i+=NT){
    float l = L[i]/tEff; u32 k = key_of(l);
    if ((int)(k>>20) == kb0) atomicAdd(&s_hist[(k>>8)&0xFFFu], 1ull);
  }
  scan_excl(s_hist, 4096, s_wsum);
  find_cross(s_hist, 4096, r, &s_fh, &s_fb);
  const int kb1 = s_fh; r -= s_fb;
  __syncthreads();

  const u32 ktop24 = ((u32)kb0<<12) | (u32)kb1;
  for (int i=tid;i<4097;i+=NT) s_hist[i]=0;
  __syncthreads();
  for (int i=tid;i<Vn;i+=NT){
    float l = L[i]/tEff; u32 k = key_of(l);
    if ((k>>8) == ktop24) atomicAdd(&s_hist[k & 0xFFu], 1ull);
  }
  scan_excl(s_hist, 256, s_wsum);
  find_cross(s_hist, 256, r, &s_fh, &s_fb);
  const u32 thrKey = (ktop24<<8) | (u32)s_fh;
  const float thr = key_to_float(thrKey);
  __syncthreads();

  for (int i=tid;i<4097;i+=NT) s_hist[i]=0;
  __syncthreads();
  for (int i=tid;i<Vn;i+=NT){
    float l = L[i]/tEff;
    if (l >= thr){
      u32 k = key_of(l);
      double sd = exp((double)l - (double)m);
      u64 qv = (u64)(sd * SCALE_D + 0.5);
      atomicAdd(&s_hist[k>>20], qv);
      if (l == m) atomicMax(&s_lastMax, i);
    }
  }
  scan_excl(s_hist, 4096, s_wsum);
  const u64 T = s_hist[4096];
  const float cf = 1.0f - top_p[b];
  const double qtd = (double)cf * (double)T;
  u64 Qfix = (qtd >= (double)T) ? T : (u64)qtd;
  const bool allmask = (Qfix >= T);

  u32 vKey = 0xFFFFFFFFu;
  int idxStar = 0x7FFFFFFF;

  if (!allmask){
    find_cross(s_hist, 4096, Qfix, &s_fh, &s_fb);
    const int g0 = s_fh;
    u64 Qrem = Qfix - s_fb;
    __syncthreads();

    for (int i=tid;i<4097;i+=NT) s_hist[i]=0;
    __syncthreads();
    for (int i=tid;i<Vn;i+=NT){
      float l = L[i]/tEff;
      if (l >= thr){
        u32 k = key_of(l);
        if ((int)(k>>20) == g0){
          double sd = exp((double)l - (double)m);
          atomicAdd(&s_hist[(k>>8)&0xFFFu], (u64)(sd*SCALE_D+0.5));
        }
      }
    }
    scan_excl(s_hist, 4096, s_wsum);
    find_cross(s_hist, 4096, Qrem, &s_fh, &s_fb);
    const int g1 = s_fh; Qrem -= s_fb;
    __syncthreads();

    const u32 ptop24 = ((u32)g0<<12)|(u32)g1;
    for (int i=tid;i<4097;i+=NT) s_hist[i]=0;
    __syncthreads();
    for (int i=tid;i<Vn;i+=NT){
      float l = L[i]/tEff;
      if (l >= thr){
        u32 k = key_of(l);
        if ((k>>8) == ptop24){
          double sd = exp((double)l - (double)m);
          atomicAdd(&s_hist[k & 0xFFu], (u64)(sd*SCALE_D+0.5));
        }
      }
    }
    scan_excl(s_hist, 256, s_wsum);
    find_cross(s_hist, 256, Qrem, &s_fh, &s_fb);
    const int g2 = s_fh;
    const u64 base2 = s_fb;
    const u64 nextPref = s_hist[g2+1];
    Qrem -= base2;
    vKey = (ptop24<<8) | (u32)g2;
    const float vStar = key_to_float(vKey);
    const double sv = exp((double)vStar - (double)m);
    const u64 qstar = (u64)(sv*SCALE_D+0.5);
    u64 nstar = (qstar > 0) ? (nextPref - base2) / qstar : 1ull;
    if (nstar < 1) nstar = 1;
    u64 tmask = (qstar > 0) ? (Qrem / qstar) : 0ull;
    if (tmask >= nstar) tmask = nstar - 1;
    idxStar = -1;
    __syncthreads();
    if (tmask >= 1){
      for (int i=tid;i<Vn;i+=NT){
        float l = L[i]/tEff;
        if (key_of(l) == vKey){
          int p = atomicAdd(&s_eqcnt, 1);
          if (p < 1024) s_eqlist[p] = i;
        }
      }
      __syncthreads();
      if (tid == 0){
        int n_ = s_eqcnt; if (n_ > 1024) n_ = 1024;
        for (int a=1;a<n_;a++){
          int key0 = s_eqlist[a]; int c2=a-1;
          while (c2>=0 && s_eqlist[c2]>key0){ s_eqlist[c2+1]=s_eqlist[c2]; c2--; }
          s_eqlist[c2+1]=key0;
        }
        int ti = (int)tmask - 1;
        if (ti >= n_) ti = n_-1;
        s_sel = s_eqlist[ti];
      }
      __syncthreads();
      idxStar = s_sel;
    }
  }

  const int lastMax = s_lastMax;
  Top5 t5; t5_init(t5);
  u64 s2 = 0;
  double br = -1.0; int bri = 0x7FFFFFFF;
  int gmin = 0x7FFFFFFF;
  for (int i=tid;i<Vn;i+=NT){
    float l = L[i]/tEff;
    u32 k = key_of(l);
    bool surv = (l >= thr) &&
                ((k > vKey) || (k == vKey && i > idxStar) || (i == lastMax));
    float val;
    if (surv){
      double sd = exp((double)l - (double)m);
      s2 += (u64)(sd*SCALE_D+0.5);
      float u = expf(l - m);
      float e = -logf(Qr[i]);
      double ratio = (double)u / (double)e;
      if (ratio > br || (ratio == br && i < bri)){ br = ratio; bri = i; }
      if (l == m && i < gmin) gmin = i;
      val = l;
    } else {
      val = -INFINITY;
    }
    t5_insert(t5, val, i);
  }
  for (int off=1; off<64; off<<=1){
    Top5 o;
    for (int j=0;j<TOPN;j++){ o.v[j]=__shfl_xor(t5.v[j],off,64); o.ix[j]=__shfl_xor(t5.ix[j],off,64); }
    for (int j=0;j<TOPN;j++) t5_insert(t5, o.v[j], o.ix[j]);
    double orr = __shfl_xor(br, off, 64);
    int ori = __shfl_xor(bri, off, 64);
    if (orr > br || (orr == br && ori < bri)){ br = orr; bri = ori; }
    int og = __shfl_xor(gmin, off, 64); if (og < gmin) gmin = og;
    s2 += __shfl_xor(s2, off, 64);
  }
  if (lane == 0){
    s_wt5[w] = t5; s_wr[w]=br; s_wri[w]=bri; s_wg[w]=gmin; s_ws2[w]=s2;
  }
  __syncthreads();
  if (tid == 0){
    Top5 f = s_wt5[0];
    double fr = s_wr[0]; int fri = s_wri[0]; int fg = s_wg[0];
    u64 fs2 = s_ws2[0];
    for (int wi=1; wi<NW; wi++){
      for (int j=0;j<TOPN;j++) t5_insert(f, s_wt5[wi].v[j], s_wt5[wi].ix[j]);
      if (s_wr[wi] > fr || (s_wr[wi]==fr && s_wri[wi]<fri)){ fr=s_wr[wi]; fri=s_wri[wi]; }
      if (s_wg[wi] < fg) fg = s_wg[wi];
      fs2 += s_ws2[wi];
    }
    double S2d = (double)fs2 / SCALE_D;
    double lS = log(S2d);
    int sampled = (tRaw < 1e-5f) ? fg : fri;
    out[b] = (float)sampled;
    for (int j=0;j<TOPN;j++){
      float lv = f.v[j];
      float lp = (lv == -INFINITY) ? NEG_BIG : (float)((double)lv - (double)m - lS);
      out[Bn + b*TOPN + j] = lp;
      out[Bn + Bn*TOPN + b*TOPN + j] = (float)f.ix[j];
    }
  }
}

__global__ __launch_bounds__(NT) void k5_rowfb(const float* __restrict__ logits,
        const float* __restrict__ temperature, const int* __restrict__ top_k,
        const float* __restrict__ top_p, const float* __restrict__ qnoise,
        const RowCtl* __restrict__ ctl, float* __restrict__ out, int Bn, int Vn){
  const int b = blockIdx.x;
  const u32 c = ctl[b].cnt0;
  if (c > 0 && c <= CAP && !ctl[b].bail) return;   // handled by k4
  fallback_row(b, logits, temperature, top_k, top_p, qnoise, out, Bn, Vn);
}

extern "C" __global__ void __launch_bounds__(NT)
sampler_fallback(const float* __restrict__ logits, const float* __restrict__ temperature,
                 const int* __restrict__ top_k, const float* __restrict__ top_p,
                 const float* __restrict__ qnoise, float* __restrict__ out, int Bn, int Vn){
  fallback_row(blockIdx.x, logits, temperature, top_k, top_p, qnoise, out, Bn, Vn);
}

// ======================= launch =======================

extern "C" void kernel_launch(void* const* d_in, const int* in_sizes, int n_in,
                              void* d_out, int out_size, void* d_ws, size_t ws_size,
                              hipStream_t stream)
{
  const float* logits      = (const float*)d_in[0];
  const float* temperature = (const float*)d_in[1];
  const int*   top_k       = (const int*)d_in[2];
  const float* top_p       = (const float*)d_in[3];
  const float* q           = (const float*)d_in[4];
  const int Bn = in_sizes[1];
  const int Vn = in_sizes[0] / Bn;

  // layout: [hist | ctl | cand] so one memset covers hist+ctl; cand needs no zeroing
  const size_t histSz  = (size_t)Bn * NB * 4;
  const size_t ctlSz   = (size_t)Bn * sizeof(RowCtl);
  const size_t offCtl  = histSz;
  const size_t offCand = histSz + ctlSz;
  const size_t total   = offCand + (size_t)Bn * CAP * 8;

  if (ws_size < total){
    sampler_fallback<<<dim3(Bn), dim3(NT), 0, stream>>>(
        logits, temperature, top_k, top_p, q, (float*)d_out, Bn, Vn);
    return;
  }

  char* wsb = (char*)d_ws;
  u32*    hist = (u32*)wsb;
  RowCtl* ctl  = (RowCtl*)(wsb + offCtl);
  u64*    cand = (u64*)(wsb + offCand);

  hipMemsetAsync(wsb, 0, offCand, stream);   // hist + ctl zeroed on DMA path
  k1_hist   <<<dim3(SL, Bn),  dim3(NT1), 0, stream>>>(logits, temperature, hist, ctl, Bn, Vn);
  k2_kb     <<<dim3(Bn),      dim3(NT),  0, stream>>>(top_k, hist, ctl, Bn, Vn);
  k3_collect<<<dim3(SL, Bn),  dim3(NT1), 0, stream>>>(logits, temperature, cand, ctl, Bn, Vn);
  k4_solve  <<<dim3(Bn),      dim3(NT1), 0, stream>>>(logits, temperature, top_k, top_p, q,
                                                      cand, ctl, (float*)d_out, Bn, Vn);
  k5_rowfb  <<<dim3(Bn),      dim3(NT),  0, stream>>>(logits, temperature, top_k, top_p, q,
                                                      ctl, (float*)d_out, Bn, Vn);
}